// Round 3
// baseline (701.425 us; speedup 1.0000x reference)
//
#include <hip/hip_runtime.h>
#include <math.h>

// DotAttention: context[b,f] = sum_t softmax_t(<hd[b],he[b,t]>) * he[b,t,f]
// Register-streamed flash-style pass1 (round-2 structure, unchanged), with
// ONE change: interleaved chunk->block mapping. Previously each of the 2048
// blocks streamed a private 256 KiB slab (2048 scattered DRAM fronts, and
// pass1 was pinned at ~1.6 TB/s across three different schedules). Now the
// 32 blocks of a batch read a contiguous, sliding 512 KiB window per
// iteration (64 dense fronts) -> DRAM row locality like the 6.4 TB/s fill.
// Online softmax is row-subset invariant, so pass2 combine is unchanged.

#define BB 64
#define TT 2048
#define FF 1024

__global__ __launch_bounds__(256) void attn_pass1(
    const float* __restrict__ hd, const float* __restrict__ he,
    float* __restrict__ part_ctx, float* __restrict__ part_m,
    float* __restrict__ part_l, int S, int Tc)
{
    const int bid  = blockIdx.x;
    const int b    = bid / S;
    const int s    = bid - b * S;
    const int lane = threadIdx.x & 63;
    const int wave = threadIdx.x >> 6;
    const int nt   = Tc >> 2;          // 16 chunks of 4 rows per block

    __shared__ __align__(16) float cbuf[4][FF];   // end-of-block combine, 16 KiB
    __shared__ float wm[4], wl[4];

    // hd fragment at this lane's float4 slots: float4 index lane + 64k
    const float* hdb = hd + (size_t)b * FF;
    float4 hdv[4];
#pragma unroll
    for (int k = 0; k < 4; ++k)
        hdv[k] = *(const float4*)(hdb + 4 * (lane + 64 * k));

    const float* heb = he + (size_t)b * TT * FF;   // batch base (no slab offset)

    // this wave's private online-softmax state
    float m = -INFINITY, l = 0.f;
    float4 ctx[4];
#pragma unroll
    for (int k = 0; k < 4; ++k) ctx[k] = make_float4(0.f, 0.f, 0.f, 0.f);

    // interleaved mapping: iteration kt -> chunk (kt*S + s), wave w owns row
    // chunk*4 + w. Batch-b blocks s=0..S-1 thus read a contiguous window.
    float4 cur[4], nxt[4];
    {
        const float* r0 = heb + ((size_t)s * 4 + wave) * FF;   // kt = 0
#pragma unroll
        for (int k = 0; k < 4; ++k)
            cur[k] = *(const float4*)(r0 + 4 * (lane + 64 * k));
    }

    for (int kt = 0; kt < nt; ++kt) {
        // prefetch next chunk's row (depth 1)
        if (kt + 1 < nt) {
            const float* rn = heb + (((size_t)(kt + 1) * S + s) * 4 + wave) * FF;
#pragma unroll
            for (int k = 0; k < 4; ++k)
                nxt[k] = *(const float4*)(rn + 4 * (lane + 64 * k));
        }

        // dot of my wave's current row with hd[b]
        float d = 0.f;
#pragma unroll
        for (int k = 0; k < 4; ++k)
            d += hdv[k].x * cur[k].x + hdv[k].y * cur[k].y +
                 hdv[k].z * cur[k].z + hdv[k].w * cur[k].w;
#pragma unroll
        for (int off = 32; off >= 1; off >>= 1)
            d += __shfl_xor(d, off, 64);

        // private online-softmax update
        const float mn    = fmaxf(m, d);
        const float alpha = __expf(m - mn);   // exp(-inf)=0 on first tile
        const float w     = __expf(d - mn);
#pragma unroll
        for (int k = 0; k < 4; ++k) {
            ctx[k].x = ctx[k].x * alpha + w * cur[k].x;
            ctx[k].y = ctx[k].y * alpha + w * cur[k].y;
            ctx[k].z = ctx[k].z * alpha + w * cur[k].z;
            ctx[k].w = ctx[k].w * alpha + w * cur[k].w;
        }
        l = l * alpha + w;
        m = mn;

#pragma unroll
        for (int k = 0; k < 4; ++k) cur[k] = nxt[k];
    }

    // ---- merge the 4 independent wave chains ----
    if (lane == 0) { wm[wave] = m; wl[wave] = l; }
    __syncthreads();
    const float M = fmaxf(fmaxf(wm[0], wm[1]), fmaxf(wm[2], wm[3]));
    const float L = wl[0] * __expf(wm[0] - M) + wl[1] * __expf(wm[1] - M) +
                    wl[2] * __expf(wm[2] - M) + wl[3] * __expf(wm[3] - M);
    const float e = __expf(m - M);        // this wave's rescale factor
#pragma unroll
    for (int k = 0; k < 4; ++k) {
        float4 c = ctx[k];
        c.x *= e; c.y *= e; c.z *= e; c.w *= e;
        *(float4*)&cbuf[wave][4 * (lane + 64 * k)] = c;
    }
    __syncthreads();

    const int j = threadIdx.x;            // owns output float4 #j
    const float4 c0 = *(const float4*)&cbuf[0][4 * j];
    const float4 c1 = *(const float4*)&cbuf[1][4 * j];
    const float4 c2 = *(const float4*)&cbuf[2][4 * j];
    const float4 c3 = *(const float4*)&cbuf[3][4 * j];
    float4 o;
    o.x = c0.x + c1.x + c2.x + c3.x;
    o.y = c0.y + c1.y + c2.y + c3.y;
    o.z = c0.z + c1.z + c2.z + c3.z;
    o.w = c0.w + c1.w + c2.w + c3.w;
    *(float4*)(part_ctx + (size_t)bid * FF + 4 * j) = o;
    if (threadIdx.x == 0) { part_m[bid] = M; part_l[bid] = L; }
}

// Pass 2: combine S chunk-partials and normalize. 4 blocks per batch.
__global__ __launch_bounds__(64) void attn_pass2(
    const float* __restrict__ part_ctx, const float* __restrict__ part_m,
    const float* __restrict__ part_l, float* __restrict__ out, int S)
{
    const int b  = blockIdx.x >> 2;
    const int f4 = ((blockIdx.x & 3) * 64 + threadIdx.x) * 4;

    float M = -INFINITY;
    for (int s = 0; s < S; ++s) M = fmaxf(M, part_m[b * S + s]);
    float L = 0.f;
    for (int s = 0; s < S; ++s)
        L += part_l[b * S + s] * __expf(part_m[b * S + s] - M);

    float4 acc = make_float4(0.f, 0.f, 0.f, 0.f);
    for (int s = 0; s < S; ++s) {
        const float e  = __expf(part_m[b * S + s] - M);
        const float4 c = *(const float4*)(part_ctx + ((size_t)(b * S + s)) * FF + f4);
        acc.x += e * c.x; acc.y += e * c.y; acc.z += e * c.z; acc.w += e * c.w;
    }
    const float inv = 1.f / L;
    *(float4*)(out + (size_t)b * FF + f4) =
        make_float4(acc.x * inv, acc.y * inv, acc.z * inv, acc.w * inv);
}

extern "C" void kernel_launch(void* const* d_in, const int* in_sizes, int n_in,
                              void* d_out, int out_size, void* d_ws, size_t ws_size,
                              hipStream_t stream) {
    const float* hd = (const float*)d_in[0];   // (64, 1024) f32
    const float* he = (const float*)d_in[1];   // (64, 2048, 1024) f32
    float* out = (float*)d_out;                // (64, 1024) f32

    // largest split count whose partials fit in the workspace
    int S = 32;
    while (S > 1 && (size_t)BB * S * (FF * sizeof(float) + 2 * sizeof(float)) > ws_size)
        S >>= 1;
    const int Tc = TT / S;   // 64 rows (16 chunks of 4) per block

    float* part_ctx = (float*)d_ws;                      // B*S*F
    float* part_m   = part_ctx + (size_t)BB * S * FF;    // B*S
    float* part_l   = part_m + (size_t)BB * S;           // B*S

    attn_pass1<<<BB * S, 256, 0, stream>>>(hd, he, part_ctx, part_m, part_l, S, Tc);
    attn_pass2<<<BB * 4, 64, 0, stream>>>(part_ctx, part_m, part_l, out, S);
}